// Round 1
// baseline (139.425 us; speedup 1.0000x reference)
//
#include <hip/hip_runtime.h>

// OverlapCalculator: pairwise IoU [50000 x 2000] fp32, row max + argmax.
// Outputs (flat fp32): pred_bbox[200000] | gt_bbox[8000] | max[50000] | argmax-as-float[50000]
//
// Numerics: must match numpy fp32 bit-exactly so argmax never flips on near-ties:
//   - same op order as ref: union = (ap + ag) - inter
//   - IEEE fp32 division (no rcp approximation)
//   - fp contract OFF so ap=(x2-x1)*(y2-y1) is not fused into the union add
//   - strict '>' ascending scan == np.argmax first-occurrence tie-break

#define N_PRED 50000
#define N_GT   2000
#define CHUNKS 8
#define CHUNK  (N_GT / CHUNKS)   // 250
#define BLOCK  256

template <int COUNT>
__device__ __forceinline__ void scan_gts(const float4* __restrict__ sg,
                                         const float* __restrict__ sa,
                                         float4 p, float ap,
                                         float& best, int& bidx) {
#pragma clang fp contract(off)
#pragma unroll 10
    for (int j = 0; j < COUNT; ++j) {
        float4 g  = sg[j];
        float ltx = fmaxf(p.x, g.x);
        float lty = fmaxf(p.y, g.y);
        float rbx = fminf(p.z, g.z);
        float rby = fminf(p.w, g.w);
        float w   = fmaxf(rbx - ltx, 0.0f);
        float h   = fmaxf(rby - lty, 0.0f);
        float inter = w * h;
        float uni   = (ap + sa[j]) - inter;   // same assoc order as np ref
        float iou   = inter / uni;            // IEEE divide, matches np bitwise
        if (iou > best) { best = iou; bidx = j; }
    }
}

// Partial kernel: grid (ceil(N_PRED/BLOCK), CHUNKS). Each block handles 256
// preds x 250 gts; gt chunk staged in LDS with precomputed areas.
__global__ __launch_bounds__(BLOCK) void iou_partial(
        const float4* __restrict__ pred, const float4* __restrict__ gt,
        float* __restrict__ ws_max, int* __restrict__ ws_idx) {
#pragma clang fp contract(off)
    __shared__ float4 sg[CHUNK];
    __shared__ float  sa[CHUNK];
    const int tid = threadIdx.x;
    const int c   = blockIdx.y;
    if (tid < CHUNK) {
        float4 g = gt[c * CHUNK + tid];
        sg[tid] = g;
        sa[tid] = (g.z - g.x) * (g.w - g.y);
    }
    __syncthreads();

    const int i = blockIdx.x * BLOCK + tid;
    if (i >= N_PRED) return;
    float4 p  = pred[i];
    float  ap = (p.z - p.x) * (p.w - p.y);
    float  best = -1.0f;
    int    bidx = 0;
    scan_gts<CHUNK>(sg, sa, p, ap, best, bidx);
    ws_max[c * N_PRED + i] = best;
    ws_idx[c * N_PRED + i] = c * CHUNK + bidx;   // global gt index
}

// Reduce over the CHUNKS partials. Ascending c + strict '>' keeps
// first-occurrence argmax semantics.
__global__ __launch_bounds__(BLOCK) void iou_reduce(
        const float* __restrict__ ws_max, const int* __restrict__ ws_idx,
        float* __restrict__ out_max, float* __restrict__ out_idx) {
    const int i = blockIdx.x * BLOCK + threadIdx.x;
    if (i >= N_PRED) return;
    float best = ws_max[i];
    int   b    = ws_idx[i];
#pragma unroll
    for (int c = 1; c < CHUNKS; ++c) {
        float v = ws_max[c * N_PRED + i];
        if (v > best) { best = v; b = ws_idx[c * N_PRED + i]; }
    }
    out_max[i] = best;
    out_idx[i] = (float)b;
}

// Fallback (workspace too small): fully fused, all 2000 gts in LDS (40 KB).
__global__ __launch_bounds__(BLOCK) void iou_direct(
        const float4* __restrict__ pred, const float4* __restrict__ gt,
        float* __restrict__ out_max, float* __restrict__ out_idx) {
#pragma clang fp contract(off)
    __shared__ float4 sg[N_GT];
    __shared__ float  sa[N_GT];
    for (int j = threadIdx.x; j < N_GT; j += BLOCK) {
        float4 g = gt[j];
        sg[j] = g;
        sa[j] = (g.z - g.x) * (g.w - g.y);
    }
    __syncthreads();

    const int i = blockIdx.x * BLOCK + threadIdx.x;
    if (i >= N_PRED) return;
    float4 p  = pred[i];
    float  ap = (p.z - p.x) * (p.w - p.y);
    float  best = -1.0f;
    int    bidx = 0;
    scan_gts<N_GT>(sg, sa, p, ap, best, bidx);
    out_max[i] = best;
    out_idx[i] = (float)bidx;
}

extern "C" void kernel_launch(void* const* d_in, const int* in_sizes, int n_in,
                              void* d_out, int out_size, void* d_ws, size_t ws_size,
                              hipStream_t stream) {
    const float4* pred = (const float4*)d_in[0];
    const float4* gt   = (const float4*)d_in[1];
    float* out = (float*)d_out;

    // Output layout (flat fp32)
    float* out_pred = out;                       // 200000
    float* out_gt   = out + 4 * N_PRED;          // 8000
    float* out_max  = out + 4 * N_PRED + 4 * N_GT;          // 50000
    float* out_idx  = out + 4 * N_PRED + 4 * N_GT + N_PRED; // 50000

    // Pass-through outputs (bit-exact copies of inputs)
    hipMemcpyAsync(out_pred, pred, (size_t)4 * N_PRED * sizeof(float),
                   hipMemcpyDeviceToDevice, stream);
    hipMemcpyAsync(out_gt, gt, (size_t)4 * N_GT * sizeof(float),
                   hipMemcpyDeviceToDevice, stream);

    const int nblk = (N_PRED + BLOCK - 1) / BLOCK;  // 196
    const size_t ws_need = (size_t)CHUNKS * N_PRED * (sizeof(float) + sizeof(int));

    if (ws_size >= ws_need) {
        float* ws_max = (float*)d_ws;
        int*   ws_idx = (int*)(ws_max + (size_t)CHUNKS * N_PRED);
        iou_partial<<<dim3(nblk, CHUNKS), BLOCK, 0, stream>>>(pred, gt, ws_max, ws_idx);
        iou_reduce<<<dim3(nblk), BLOCK, 0, stream>>>(ws_max, ws_idx, out_max, out_idx);
    } else {
        iou_direct<<<dim3(nblk), BLOCK, 0, stream>>>(pred, gt, out_max, out_idx);
    }
}

// Round 2
// 137.653 us; speedup vs baseline: 1.0129x; 1.0129x over previous
//
#include <hip/hip_runtime.h>

// OverlapCalculator: pairwise IoU [50000 x 2000] fp32, row max + argmax.
// Outputs (flat fp32): pred_bbox[200000] | gt_bbox[8000] | max[50000] | argmax-as-float[50000]
//
// Bit-exactness strategy (absmax must be 0 on max, and argmax must never flip):
//   - same op order as np ref: union = (ap + ag) - inter, fp contract OFF
//   - divides that actually happen are plain IEEE fp32 '/'
//   - running max uses a SOUND skip filter:  skip iff inter <= fl(fl(best*K)*uni),
//     K = 1-3.6e-7. Then inter/uni <= best*(1-3.6e-7)(1+1.2e-7) => fl(inter/uni) < best,
//     so skipping never drops a true update; the taken path re-checks with the exact
//     IEEE quotient and strict '>', preserving np.argmax first-occurrence semantics.
//   - chunks reduced in ascending order with strict '>' keep earliest-index ties.

#define N_PRED 50000
#define N_GT   2000
#define CHUNKS 4
#define CHUNK  (N_GT / CHUNKS)   // 500
#define BLOCK  256
#define KFILT  0.99999964f       // 1 - 3.6e-7

// --- setup: precompute gt areas (bit-exact same expression as ref) ----------
__global__ __launch_bounds__(BLOCK) void gt_areas_kernel(
        const float4* __restrict__ gt, float* __restrict__ areas) {
#pragma clang fp contract(off)
    int j = blockIdx.x * BLOCK + threadIdx.x;
    if (j < N_GT) {
        float4 g = gt[j];
        areas[j] = (g.z - g.x) * (g.w - g.y);
    }
}

// --- partial: grid (196, CHUNKS); one thread per pred, CHUNK gts ------------
__global__ __launch_bounds__(BLOCK) void iou_partial(
        const float4* __restrict__ pred, const float4* __restrict__ gt,
        const float* __restrict__ areas,
        float* __restrict__ ws_max, int* __restrict__ ws_idx) {
#pragma clang fp contract(off)
    const int i = blockIdx.x * BLOCK + threadIdx.x;
    if (i >= N_PRED) return;
    const int c    = blockIdx.y;
    const int base = c * CHUNK;

    const float4 p  = pred[i];
    const float  ap = (p.z - p.x) * (p.w - p.y);

    float best  = -1.0f;            // j=0 always takes the divide path once
    float bestp = -KFILT;           // best * KFILT
    int   bidx  = base;

#pragma unroll 10
    for (int j = 0; j < CHUNK; ++j) {
        // wave-uniform index -> scalar/broadcast loads, no LDS
        const float4 g  = gt[base + j];
        const float  ag = areas[base + j];
        float ltx = fmaxf(p.x, g.x);
        float lty = fmaxf(p.y, g.y);
        float rbx = fminf(p.z, g.z);
        float rby = fminf(p.w, g.w);
        float w   = fmaxf(rbx - ltx, 0.0f);
        float h   = fmaxf(rby - lty, 0.0f);
        float inter = w * h;
        float uni   = (ap + ag) - inter;       // same assoc order as np ref
        // sound filter: false => fl(inter/uni) < best guaranteed
        if (inter > bestp * uni) {
            float iou = inter / uni;           // exact IEEE divide (rare)
            if (iou > best) {
                best  = iou;
                bestp = iou * KFILT;
                bidx  = base + j;
            }
        }
    }
    ws_max[c * N_PRED + i] = best;
    ws_idx[c * N_PRED + i] = bidx;
}

// --- reduce over chunks + passthrough copies (fused to cut graph nodes) -----
__global__ __launch_bounds__(BLOCK) void iou_reduce_copy(
        const float* __restrict__ ws_max, const int* __restrict__ ws_idx,
        const float4* __restrict__ pred, const float4* __restrict__ gt,
        float* __restrict__ out) {
    const int i = blockIdx.x * BLOCK + threadIdx.x;
    float4* out_pred = (float4*)out;                    // 50000 float4
    float4* out_gt   = (float4*)(out + 4 * N_PRED);     // 2000 float4
    float*  out_max  = out + 4 * N_PRED + 4 * N_GT;     // 50000
    float*  out_idx  = out_max + N_PRED;                // 50000

    if (i < N_GT) out_gt[i] = gt[i];
    if (i >= N_PRED) return;
    out_pred[i] = pred[i];

    float best = ws_max[i];
    int   b    = ws_idx[i];
#pragma unroll
    for (int c = 1; c < CHUNKS; ++c) {
        float v = ws_max[c * N_PRED + i];
        if (v > best) { best = v; b = ws_idx[c * N_PRED + i]; }
    }
    out_max[i] = best;
    out_idx[i] = (float)b;
}

extern "C" void kernel_launch(void* const* d_in, const int* in_sizes, int n_in,
                              void* d_out, int out_size, void* d_ws, size_t ws_size,
                              hipStream_t stream) {
    const float4* pred = (const float4*)d_in[0];
    const float4* gt   = (const float4*)d_in[1];
    float* out = (float*)d_out;

    // workspace layout: areas[2048 pad] | ws_max[CHUNKS*N_PRED] | ws_idx[CHUNKS*N_PRED]
    float* areas  = (float*)d_ws;
    float* ws_max = areas + 2048;
    int*   ws_idx = (int*)(ws_max + (size_t)CHUNKS * N_PRED);

    const int nblk = (N_PRED + BLOCK - 1) / BLOCK;  // 196

    gt_areas_kernel<<<dim3((N_GT + BLOCK - 1) / BLOCK), BLOCK, 0, stream>>>(gt, areas);
    iou_partial<<<dim3(nblk, CHUNKS), BLOCK, 0, stream>>>(pred, gt, areas, ws_max, ws_idx);
    iou_reduce_copy<<<dim3(nblk), BLOCK, 0, stream>>>(ws_max, ws_idx, pred, gt, out);
}